// Round 1
// baseline (1199.956 us; speedup 1.0000x reference)
//
#include <hip/hip_runtime.h>
#include <hip/hip_bf16.h>

// AsyncIOPool: out = concat( src[index], dst.at[dst_index].set(push_src) )
// Pure HBM-bound data movement. One wave (64 lanes) per 256-float row;
// each lane moves one float4 (16 B) -> 1 KB coalesced per row.

__global__ void init_inv_kernel(int* __restrict__ inv, int n) {
    int i = blockIdx.x * blockDim.x + threadIdx.x;
    if (i < n) inv[i] = -1;
}

__global__ void scatter_inv_kernel(const int* __restrict__ dst_index,
                                   int* __restrict__ inv, int b) {
    int i = blockIdx.x * blockDim.x + threadIdx.x;
    if (i < b) inv[dst_index[i]] = i;   // dst_index rows are unique: no race
}

// One wave per output row r in [0, B+N):
//   r <  B : out[r] = src[index[r]]
//   r >= B : j = r-B; out[r] = (inv[j] >= 0) ? push_src[inv[j]] : dst[j]
__global__ __launch_bounds__(256) void fused_copy_kernel(
        const float4* __restrict__ src,
        const float4* __restrict__ push_src,
        const float4* __restrict__ dst,
        const int* __restrict__ index,
        const int* __restrict__ inv,
        float4* __restrict__ out,
        int B, int R, int D4) {
    int gtid = blockIdx.x * blockDim.x + threadIdx.x;
    int wave = gtid >> 6;          // one 64-lane wave per row
    int lane = threadIdx.x & 63;
    if (wave >= R) return;

    const float4* srow;
    if (wave < B) {
        int idx = index[wave];                       // wave-uniform broadcast
        srow = src + (size_t)idx * D4;
    } else {
        int j = wave - B;
        int i = inv[j];                              // wave-uniform broadcast
        srow = (i >= 0) ? (push_src + (size_t)i * D4)
                        : (dst      + (size_t)j * D4);
    }
    float4* orow = out + (size_t)wave * D4;
    // D4 == 64 for D=256: exactly one float4 per lane. Loop kept for generality.
    for (int c = lane; c < D4; c += 64) {
        orow[c] = srow[c];
    }
}

extern "C" void kernel_launch(void* const* d_in, const int* in_sizes, int n_in,
                              void* d_out, int out_size, void* d_ws, size_t ws_size,
                              hipStream_t stream) {
    // setup_inputs() order: src[N*D], push_src[B*D], dst[N*D], index[B], dst_index[B]
    const float* src      = (const float*)d_in[0];
    const float* push_src = (const float*)d_in[1];
    const float* dst      = (const float*)d_in[2];
    const int*   index    = (const int*)d_in[3];
    const int*   dst_idx  = (const int*)d_in[4];

    const int B = in_sizes[3];                 // 131072
    const int D = in_sizes[1] / B;             // 256
    const int N = in_sizes[0] / D;             // 500000
    const int D4 = D / 4;                      // 64 float4 per row
    const int R = B + N;                       // total output rows

    int* inv = (int*)d_ws;                     // N ints (2 MB) of scratch

    // 1) inv[j] = -1  (d_ws is re-poisoned every launch; must re-init)
    {
        int threads = 256, blocks = (N + threads - 1) / threads;
        init_inv_kernel<<<blocks, threads, 0, stream>>>(inv, N);
    }
    // 2) inv[dst_index[i]] = i
    {
        int threads = 256, blocks = (B + threads - 1) / threads;
        scatter_inv_kernel<<<blocks, threads, 0, stream>>>(dst_idx, inv, B);
    }
    // 3) fused single-pass write of all B+N output rows
    {
        int threads = 256;                     // 4 waves/block -> 4 rows/block
        long long total_threads = (long long)R * 64;
        int blocks = (int)((total_threads + threads - 1) / threads);
        fused_copy_kernel<<<blocks, threads, 0, stream>>>(
            (const float4*)src, (const float4*)push_src, (const float4*)dst,
            index, inv, (float4*)d_out, B, R, D4);
    }
}